// Round 11
// baseline (67.925 us; speedup 1.0000x reference)
//
#include <hip/hip_runtime.h>
#include <cstdint>
#include <cstddef>

#define BB 32
#define NN 4096
#define DD 256
#define KK 16

constexpr float FEPS = 1e-12f;

__device__ __forceinline__ float dot4(float4 a, float4 b) {
  return a.x*b.x + a.y*b.y + a.z*b.z + a.w*b.w;
}
__device__ __forceinline__ float4 f4add(float4 a, float4 b) {
  return make_float4(a.x+b.x, a.y+b.y, a.z+b.z, a.w+b.w);
}
__device__ __forceinline__ float4 f4fma(float s, float4 x, float4 a) {
  a.x += s*x.x; a.y += s*x.y; a.z += s*x.z; a.w += s*x.w; return a;
}

// ---------------------------------------------------------------------------
// Fused kernel (r7 base): TILE tokens per block, 256 threads, 8 blk/CU.
// Phase A: thread = (token, k-group); x staged via double-buffered 16-dim LDS
//          chunks with a 3-DEEP load ring (chunk c+3 issued at chunk c, its
//          ds_write 2 chunks later -> ~2 chunk-times of HBM-latency cover).
// Phase B: wave = k-quad over all TILE tokens, 4-deep per-wave pipeline PLUS
//          4*wave token stagger -> 16 distinct rows in flight per block.
// ---------------------------------------------------------------------------
template <int TILE>
__global__ __launch_bounds__(256, (TILE == 64 ? 8 : 4)) void fused_kernel(
    const float* __restrict__ x, const int* __restrict__ mask,
    const float* __restrict__ W, const float* __restrict__ bias,
    float* __restrict__ outv, float* __restrict__ outs, int partial_mode)
{
  constexpr int NG    = 256 / TILE;     // k-groups (thread layers)
  constexpr int KPT   = KK / NG;        // k per thread in Phase A
  constexpr int SW4   = TILE / 64;      // staging float4s per thread per chunk
  constexpr int WPG   = 4 / NG;         // waves per k-group
  constexpr int TPBAT = NN / TILE;

  __shared__ float4 xs4[2][TILE * 5];   // 2 x 5*TILE float4 (pad 4->5)
  __shared__ float  al[TILE * KK];
  __shared__ float  psum[TILE][NG];
  __shared__ float  asacc[WPG][KK];

  const int tid  = threadIdx.x;
  const int lane = tid & 63;
  const int wave = tid >> 6;
  const int tok  = tid & (TILE - 1);
  const int kg   = __builtin_amdgcn_readfirstlane(tid / TILE);
  const int slot = __builtin_amdgcn_readfirstlane(wave & (WPG - 1));

  const int tile = blockIdx.x;
  const int b    = tile / TPBAT;
  const int n0   = (tile % TPBAT) * TILE;

  const float4* xb4 = reinterpret_cast<const float4*>(x + ((size_t)b*NN + n0)*DD);
  const int*    mb  = mask + (size_t)b*NN + n0;

  // ---------------- Phase A: KPT logits per thread, 3-deep staging --------
  float part[KPT];
#pragma unroll
  for (int q = 0; q < KPT; ++q) part[q] = bias[kg * KPT + q];

  const int st = tid >> 2;              // staging token (0..63)
  const int sj = tid & 3;               // staging float4 col within chunk

  float4 s1[SW4], s2[SW4], s3[SW4];

  // prologue: chunk 0 -> LDS buf0; chunks 1,2 in flight in regs
  {
    float4 p0[SW4];
#pragma unroll
    for (int l = 0; l < SW4; ++l)
      p0[l] = xb4[(size_t)(st + l * 64) * 64 + sj];
#pragma unroll
    for (int l = 0; l < SW4; ++l)
      xs4[0][(st + l * 64) * 5 + sj] = p0[l];
#pragma unroll
    for (int l = 0; l < SW4; ++l)
      s1[l] = xb4[(size_t)(st + l * 64) * 64 + 4 + sj];
#pragma unroll
    for (int l = 0; l < SW4; ++l)
      s2[l] = xb4[(size_t)(st + l * 64) * 64 + 8 + sj];
  }

#pragma unroll 1
  for (int c = 0; c < 16; ++c) {        // 16 chunks of 16 dims
    __syncthreads();                    // chunk c (and its buffer) ready

    if (c + 3 < 16) {                   // issue chunk c+3 (2-chunk cover)
#pragma unroll
      for (int l = 0; l < SW4; ++l)
        s3[l] = xb4[(size_t)(st + l * 64) * 64 + (c + 3) * 4 + sj];
    }
    if (c + 1 < 16) {                   // land chunk c+1 (issued at c-2)
#pragma unroll
      for (int l = 0; l < SW4; ++l)
        xs4[(c + 1) & 1][(st + l * 64) * 5 + sj] = s1[l];
    }

#pragma unroll
    for (int j = 0; j < 4; ++j) {       // compute on chunk c
      const float4 xv = xs4[c & 1][tok * 5 + j];
      const float* Wc = W + c * 16 + j * 4;
#pragma unroll
      for (int q = 0; q < KPT; ++q) {
        const float4 wv = *reinterpret_cast<const float4*>(Wc + (kg * KPT + q) * DD);
        part[q] += dot4(xv, wv);
      }
    }

#pragma unroll
    for (int l = 0; l < SW4; ++l) { s1[l] = s2[l]; s2[l] = s3[l]; }
  }

  // masked softmax across NG thread-layers via psum exchange
  float e[KPT], pexp = 0.f;
#pragma unroll
  for (int q = 0; q < KPT; ++q) { e[q] = __expf(part[q]); pexp += e[q]; }
  psum[tok][kg] = pexp;
  __syncthreads();
  float a[KPT];
  {
    float denom = 0.f;
#pragma unroll
    for (int g = 0; g < NG; ++g) denom += psum[tok][g];
    const float r = mb[tok] ? (1.0f / denom) : 0.0f;
#pragma unroll
    for (int q = 0; q < KPT; ++q) a[q] = e[q] * r;
#pragma unroll
    for (int q4 = 0; q4 < KPT; q4 += 4)
      *reinterpret_cast<float4*>(&al[tok * KK + kg * KPT + q4]) =
          make_float4(a[q4], a[q4+1], a[q4+2], a[q4+3]);
  }

  // asum: butterfly over 64 lanes (= 64 distinct tokens per wave)
  {
    float red[KPT];
#pragma unroll
    for (int q = 0; q < KPT; ++q) red[q] = a[q];
#pragma unroll
    for (int off = 32; off >= 1; off >>= 1)
#pragma unroll
      for (int q = 0; q < KPT; ++q) red[q] += __shfl_xor(red[q], off);
    if (lane == 0)
#pragma unroll
      for (int q = 0; q < KPT; ++q) asacc[slot][kg * KPT + q] = red[q];
  }
  __syncthreads();

  // ------ Phase B: wave = k-quad, token order staggered by 4*wave ---------
  float4 acc0 = make_float4(0.f,0.f,0.f,0.f);
  float4 acc1 = make_float4(0.f,0.f,0.f,0.f);
  float4 acc2 = make_float4(0.f,0.f,0.f,0.f);
  float4 acc3 = make_float4(0.f,0.f,0.f,0.f);

  const float4* xw = xb4 + lane;        // lane owns dims 4*lane..4*lane+3
  const int kq4   = 4 * wave;           // this wave's k-quad offset in al row
  const int tbase = 4 * wave;           // stagger: 16 distinct rows/block

  float4 w0 = xw[((tbase + 0) & (TILE - 1)) * 64];
  float4 w1 = xw[((tbase + 1) & (TILE - 1)) * 64];
  float4 w2 = xw[((tbase + 2) & (TILE - 1)) * 64];
  float4 w3 = xw[((tbase + 3) & (TILE - 1)) * 64];

#pragma unroll 4
  for (int tt = 0; tt < TILE - 4; ++tt) {
    const int t  = (tt + tbase) & (TILE - 1);
    const int tn = (tt + 4 + tbase) & (TILE - 1);
    const float4 nx = xw[tn * 64];
    const float4 av = *reinterpret_cast<const float4*>(&al[t * KK + kq4]);
    acc0 = f4fma(av.x, w0, acc0);
    acc1 = f4fma(av.y, w0, acc1);
    acc2 = f4fma(av.z, w0, acc2);
    acc3 = f4fma(av.w, w0, acc3);
    w0 = w1; w1 = w2; w2 = w3; w3 = nx;
  }
#pragma unroll
  for (int tt = TILE - 4; tt < TILE; ++tt) {
    const int t = (tt + tbase) & (TILE - 1);
    const float4 av = *reinterpret_cast<const float4*>(&al[t * KK + kq4]);
    acc0 = f4fma(av.x, w0, acc0);
    acc1 = f4fma(av.y, w0, acc1);
    acc2 = f4fma(av.z, w0, acc2);
    acc3 = f4fma(av.w, w0, acc3);
    w0 = w1; w1 = w2; w2 = w3;
  }

  // ------------- output ----------------------------------------------------
  const int kq = wave * 4;
  if (partial_mode) {
    float4* dst = reinterpret_cast<float4*>(outv + (size_t)tile * KK * DD);
    dst[(kq + 0) * 64 + lane] = acc0;
    dst[(kq + 1) * 64 + lane] = acc1;
    dst[(kq + 2) * 64 + lane] = acc2;
    dst[(kq + 3) * 64 + lane] = acc3;
    if (tid < KK) {
      float s = 0.f;
#pragma unroll
      for (int sl = 0; sl < WPG; ++sl) s += asacc[sl][tid];
      outs[tile * KK + tid] = s;
    }
  } else {
    float* vb = outv + (size_t)b * KK * DD;
    const float4 aa4[4] = {acc0, acc1, acc2, acc3};
#pragma unroll
    for (int i = 0; i < 4; ++i) {
      float* p = vb + (kq + i) * DD + 4 * lane;
      atomicAdd(p + 0, aa4[i].x);
      atomicAdd(p + 1, aa4[i].y);
      atomicAdd(p + 2, aa4[i].z);
      atomicAdd(p + 3, aa4[i].w);
    }
    if (tid < KK) {
      float s = 0.f;
#pragma unroll
      for (int sl = 0; sl < WPG; ++sl) s += asacc[sl][tid];
      atomicAdd(&outs[b * KK + tid], s);
    }
  }
}

// ---------------------------------------------------------------------------
// Finalize A (BB*KK blocks x 256 thr): block = (b,k). float4 slice-sum with
// 4 slice-groups x 4 accumulators, LDS combine, ssum by wave butterfly.
// ---------------------------------------------------------------------------
__global__ __launch_bounds__(256) void finalizeA_kernel(
    const float* __restrict__ pv, const float* __restrict__ ps,
    const float* __restrict__ cent, float* __restrict__ vtmp,
    float* __restrict__ ssbuf, int nslice)
{
  const int blk = blockIdx.x;
  const int b   = blk >> 4;
  const int k   = blk & 15;
  const int tid = threadIdx.x;
  const int sg  = tid >> 6;           // slice group 0..3
  const int ld  = tid & 63;           // float4 dim index

  __shared__ float4 cmbA[3][64];

  float pval = 0.f;
  for (int s = ld; s < nslice; s += 64)
    pval += ps[(size_t)(b * nslice + s) * KK + k];
#pragma unroll
  for (int off = 32; off >= 1; off >>= 1) pval += __shfl_xor(pval, off);
  const float ssum = pval;

  const float4* pv4 = reinterpret_cast<const float4*>(pv);
  const size_t base = ((size_t)b * nslice * KK + k) * 64 + ld;
  float4 a0 = make_float4(0.f,0.f,0.f,0.f), a1 = a0, a2 = a0, a3 = a0;
  int s = sg;
  for (; s + 12 < nslice; s += 16) {
    a0 = f4add(a0, pv4[base + (size_t)(s     ) * (KK * 64)]);
    a1 = f4add(a1, pv4[base + (size_t)(s +  4) * (KK * 64)]);
    a2 = f4add(a2, pv4[base + (size_t)(s +  8) * (KK * 64)]);
    a3 = f4add(a3, pv4[base + (size_t)(s + 12) * (KK * 64)]);
  }
  for (; s < nslice; s += 4)
    a0 = f4add(a0, pv4[base + (size_t)s * (KK * 64)]);
  float4 tot = f4add(f4add(a0, a1), f4add(a2, a3));

  if (sg > 0) cmbA[sg - 1][ld] = tot;
  __syncthreads();

  if (sg == 0) {
    tot = f4add(tot, f4add(cmbA[0][ld], f4add(cmbA[1][ld], cmbA[2][ld])));
    const float4 cv = reinterpret_cast<const float4*>(cent)[k * 64 + ld];
    float4 v;
    v.x = tot.x - ssum * cv.x;
    v.y = tot.y - ssum * cv.y;
    v.z = tot.z - ssum * cv.z;
    v.w = tot.w - ssum * cv.w;
    reinterpret_cast<float4*>(vtmp)[((size_t)b * KK + k) * 64 + ld] = v;
    float p = dot4(v, v);
#pragma unroll
    for (int off = 32; off >= 1; off >>= 1) p += __shfl_xor(p, off);
    if (ld == 0) ssbuf[blk] = p;
  }
}

// ---------------------------------------------------------------------------
// Finalize B (BB blocks x 1024 thr): intra-cluster + global L2 normalize.
// ---------------------------------------------------------------------------
__global__ __launch_bounds__(1024) void finalizeB_kernel(
    const float* __restrict__ vtmp, const float* __restrict__ ssbuf,
    float* __restrict__ out)
{
  const int b    = blockIdx.x;
  const int tid  = threadIdx.x;
  const int d    = tid & 255;
  const int kq   = tid >> 8;
  const int lane = tid & 63;
  const int w    = tid >> 6;

  __shared__ float redB[16];
  __shared__ float gsh;

  float u[4];
  float p2 = 0.f;
#pragma unroll
  for (int kk = 0; kk < 4; ++kk) {
    const int k = kq * 4 + kk;
    const float rk = 1.0f / fmaxf(sqrtf(ssbuf[b * KK + k]), FEPS);
    u[kk] = vtmp[((size_t)b * KK + k) * DD + d] * rk;
    p2 += u[kk] * u[kk];
  }
#pragma unroll
  for (int off = 32; off >= 1; off >>= 1) p2 += __shfl_xor(p2, off);
  if (lane == 0) redB[w] = p2;
  __syncthreads();

  if (tid == 0) {
    float g = 0.f;
#pragma unroll
    for (int i = 0; i < 16; ++i) g += redB[i];
    gsh = 1.0f / fmaxf(sqrtf(g), FEPS);
  }
  __syncthreads();

  const float g = gsh;
#pragma unroll
  for (int kk = 0; kk < 4; ++kk) {
    const int k = kq * 4 + kk;
    out[(size_t)b * KK * DD + k * DD + d] = u[kk] * g;
  }
}

extern "C" void kernel_launch(void* const* d_in, const int* in_sizes, int n_in,
                              void* d_out, int out_size, void* d_ws, size_t ws_size,
                              hipStream_t stream) {
  const float* x    = (const float*)d_in[0];
  const int*   mask = (const int*)d_in[1];
  const float* W    = (const float*)d_in[2];
  const float* bias = (const float*)d_in[3];
  const float* cent = (const float*)d_in[4];
  float* out = (float*)d_out;

  const size_t vtmpN = (size_t)BB * KK * DD;
  const size_t ssN   = (size_t)BB * KK;

  const size_t t64   = (size_t)BB * (NN / 64);    // 2048 tiles
  const size_t t128  = (size_t)BB * (NN / 128);   // 1024 tiles
  const size_t need64  = (t64  * KK * DD + t64  * KK + vtmpN + ssN) * sizeof(float);
  const size_t need128 = (t128 * KK * DD + t128 * KK + vtmpN + ssN) * sizeof(float);

  if (ws_size >= need64) {
    float* pv    = (float*)d_ws;
    float* ps    = pv + t64 * KK * DD;
    float* vtmp  = ps + t64 * KK;
    float* ssbuf = vtmp + vtmpN;
    fused_kernel<64><<<(int)t64, 256, 0, stream>>>(x, mask, W, bias, pv, ps, 1);
    finalizeA_kernel<<<BB * KK, 256, 0, stream>>>(pv, ps, cent, vtmp, ssbuf, NN / 64);
    finalizeB_kernel<<<BB, 1024, 0, stream>>>(vtmp, ssbuf, out);
  } else if (ws_size >= need128) {
    float* pv    = (float*)d_ws;
    float* ps    = pv + t128 * KK * DD;
    float* vtmp  = ps + t128 * KK;
    float* ssbuf = vtmp + vtmpN;
    fused_kernel<128><<<(int)t128, 256, 0, stream>>>(x, mask, W, bias, pv, ps, 1);
    finalizeA_kernel<<<BB * KK, 256, 0, stream>>>(pv, ps, cent, vtmp, ssbuf, NN / 128);
    finalizeB_kernel<<<BB, 1024, 0, stream>>>(vtmp, ssbuf, out);
  } else {
    float* vacc  = (float*)d_ws;                 // [BB][KK][DD]
    float* sacc  = vacc + vtmpN;                 // [BB][KK]
    float* vtmp  = sacc + ssN;
    float* ssbuf = vtmp + vtmpN;
    hipMemsetAsync(d_ws, 0, (vtmpN + ssN) * sizeof(float), stream);
    fused_kernel<64><<<(int)t64, 256, 0, stream>>>(x, mask, W, bias, vacc, sacc, 0);
    finalizeA_kernel<<<BB * KK, 256, 0, stream>>>(vacc, sacc, cent, vtmp, ssbuf, 1);
    finalizeB_kernel<<<BB, 1024, 0, stream>>>(vtmp, ssbuf, out);
  }
}